// Round 2
// 1101.143 us; speedup vs baseline: 1.2169x; 1.2169x over previous
//
#include <hip/hip_runtime.h>
#include <cstdint>
#include <cstddef>

// Problem shape (fixed by the reference): E=1.6M, D=64, H=128, N=100k.
#define D_FEAT 64
#define H_HID 128

// ---------------------------------------------------------------------------
// Workspace (13.6 MB): deg[N], off[N], btot[1024], bbase[1024], elist[2E].
// flow[N][64] lives in d_out (gather writes it, MLP reads row n before
// overwriting row n -- same thread-quad, program order).
// ---------------------------------------------------------------------------

// 1. Count incidences (3.2M int atomics into 400KB, L2-resident).
__global__ __launch_bounds__(256) void count_deg_kernel(
    const int* __restrict__ idx, int* __restrict__ deg, int twoE) {
  int t = blockIdx.x * 256 + threadIdx.x;
  if (t < twoE) atomicAdd(&deg[idx[t]], 1);
}

// 2a. Per-block (1024-wide) exclusive scan + block totals.
__global__ __launch_bounds__(1024) void scanA_kernel(
    const int* __restrict__ deg, int* __restrict__ off,
    int* __restrict__ btot, int N) {
  __shared__ int s[1024];
  int i = blockIdx.x * 1024 + threadIdx.x;
  int v = (i < N) ? deg[i] : 0;
  s[threadIdx.x] = v;
  __syncthreads();
  for (int d = 1; d < 1024; d <<= 1) {
    int t = (threadIdx.x >= d) ? s[threadIdx.x - d] : 0;
    __syncthreads();
    s[threadIdx.x] += t;
    __syncthreads();
  }
  if (i < N) off[i] = s[threadIdx.x] - v;       // exclusive within block
  if (threadIdx.x == 1023) btot[blockIdx.x] = s[1023];
}

// 2b. Exclusive scan of block totals (nb <= 1024), one block.
__global__ __launch_bounds__(1024) void scanB_kernel(
    const int* __restrict__ btot, int* __restrict__ bbase, int nb) {
  __shared__ int s[1024];
  int v = (threadIdx.x < nb) ? btot[threadIdx.x] : 0;
  s[threadIdx.x] = v;
  __syncthreads();
  for (int d = 1; d < 1024; d <<= 1) {
    int t = (threadIdx.x >= d) ? s[threadIdx.x - d] : 0;
    __syncthreads();
    s[threadIdx.x] += t;
    __syncthreads();
  }
  if (threadIdx.x < nb) bbase[threadIdx.x] = s[threadIdx.x] - v;
}

// 2c. Add block bases -> global exclusive offsets.
__global__ __launch_bounds__(256) void scanC_kernel(
    int* __restrict__ off, const int* __restrict__ bbase, int N) {
  int i = blockIdx.x * 256 + threadIdx.x;
  if (i < N) off[i] += bbase[i >> 10];
}

// 3. Fill adjacency via destructive atomic cursors: afterwards off[n] is the
// END of node n's segment; start = off[n] - deg[n].
__global__ __launch_bounds__(256) void fill_kernel(
    const int* __restrict__ idx, int* __restrict__ off,
    int* __restrict__ elist, int E) {
  int t = blockIdx.x * 256 + threadIdx.x;
  if (t >= 2 * E) return;
  int node = idx[t];
  int e = (t < E) ? t : t - E;
  int pos = atomicAdd(&off[node], 1);
  elist[pos] = e;
}

// 4. Gather-only: one wave per node, 4 waves/block. 16-lane groups pull whole
// 256B attr rows (float4/lane, coalesced); xor-shuffle reduce; lanes 0..15
// store the 256B flow row.
__global__ __launch_bounds__(256) void gather_kernel(
    const int* __restrict__ deg, const int* __restrict__ off_end,
    const int* __restrict__ elist, const float* __restrict__ attr,
    float* __restrict__ flow, int N) {
  int wave = threadIdx.x >> 6;
  int lane = threadIdx.x & 63;
  int n = blockIdx.x * 4 + wave;
  if (n >= N) return;

  int end = off_end[n];
  int start = end - deg[n];
  int g = lane >> 4;   // edge subgroup 0..3
  int l = lane & 15;   // float4 slot within the 256B row

  float a0 = 0.f, a1 = 0.f, a2 = 0.f, a3 = 0.f;
  int p = start + g;
  for (; p + 4 < end; p += 8) {
    int e0 = elist[p];
    int e1 = elist[p + 4];
    float4 v0 = reinterpret_cast<const float4*>(attr)[(size_t)e0 * 16 + l];
    float4 v1 = reinterpret_cast<const float4*>(attr)[(size_t)e1 * 16 + l];
    a0 += v0.x + v1.x; a1 += v0.y + v1.y;
    a2 += v0.z + v1.z; a3 += v0.w + v1.w;
  }
  if (p < end) {
    int e0 = elist[p];
    float4 v0 = reinterpret_cast<const float4*>(attr)[(size_t)e0 * 16 + l];
    a0 += v0.x; a1 += v0.y; a2 += v0.z; a3 += v0.w;
  }
  a0 += __shfl_xor(a0, 16); a0 += __shfl_xor(a0, 32);
  a1 += __shfl_xor(a1, 16); a1 += __shfl_xor(a1, 32);
  a2 += __shfl_xor(a2, 16); a2 += __shfl_xor(a2, 32);
  a3 += __shfl_xor(a3, 16); a3 += __shfl_xor(a3, 32);

  if (g == 0) {
    reinterpret_cast<float4*>(flow)[(size_t)n * 16 + l] =
        make_float4(a0, a1, a2, a3);
  }
}

// ---------------------------------------------------------------------------
// 5. MLP, spill-free: 4 lanes per node (q = lane&3).
//    Lane q: h[32] = relu(x @ W1[:, 32q:32q+32] + b1)   (k-quarter)
//            acc[64] = partial of ALL 64 outputs over its 32 k's, stored in a
//            lane-rotated register order so the reduce-scatter uses only
//            STATIC register indices:
//              reg r  <->  global j = 32*((q>>1)^(r>>5)) | ((16(q&1)+(r&31))&31)
//    Reduce-scatter: acc[r]   += shfl_xor(acc[32+r], 2)   (r<32)
//                    acc[r]   += shfl_xor(acc[16+r], 1)   (r<16)
//    -> lane q holds final out[16q .. 16q+16), stored as 4 coalesced float4.
//    Peak live regs ~112 (h32+acc64+addr) -> no scratch even at a 128 budget.
//    LDS: W1 rows padded to 160 f (quarters at +40 f -> banks 0/8/16/24),
//         W2 quarters padded to 2056 f (banks 0/24/16/8 incl. j-rotation).
//    Per-node FMA/ds_read counts identical to the old kernel; only the
//    spill traffic and the strided stores are removed.
// ---------------------------------------------------------------------------
__global__ __launch_bounds__(256, 2) void mlp4_kernel(
    const float* __restrict__ W1, const float* __restrict__ b1,
    const float* __restrict__ W2, const float* __restrict__ b2,
    float* __restrict__ out, int N) {
  __shared__ __align__(16) float sW1[64 * 160];   // [i][quarter(40f)]; 40.96KB
  __shared__ __align__(16) float sW2[4 * 2056];   // [quarter][k&31][64]; 32.9KB
  __shared__ __align__(16) float sB1[H_HID];
  __shared__ __align__(16) float sB2[D_FEAT];

  for (int t = threadIdx.x; t < 64 * 128; t += 256) {
    int i = t >> 7, k = t & 127;
    sW1[i * 160 + (k >> 5) * 40 + (k & 31)] = W1[t];
  }
  for (int t = threadIdx.x; t < 128 * 64; t += 256) {
    int k = t >> 6, j = t & 63;
    sW2[(k >> 5) * 2056 + (k & 31) * 64 + j] = W2[t];
  }
  if (threadIdx.x < H_HID) sB1[threadIdx.x] = b1[threadIdx.x];
  if (threadIdx.x < D_FEAT) sB2[threadIdx.x] = b2[threadIdx.x];
  __syncthreads();

  int n = blockIdx.x * 64 + (threadIdx.x >> 2);   // node
  int q = threadIdx.x & 3;                        // k-quarter / j-slice
  if (n >= N) return;

  const float* xrow = out + (size_t)n * D_FEAT;   // flow row (read-before-write)

  // ---- Phase 1: h[32] = b1 quarter ----------------------------------------
  float h[32];
  {
    const float4* b1q = reinterpret_cast<const float4*>(sB1 + (q << 5));
#pragma unroll
    for (int v = 0; v < 8; ++v) {
      float4 b = b1q[v];
      h[4 * v + 0] = b.x; h[4 * v + 1] = b.y;
      h[4 * v + 2] = b.z; h[4 * v + 3] = b.w;
    }
  }
  const float* w1q = sW1 + q * 40;
  for (int ii = 0; ii < 16; ++ii) {               // dynamic: small code
    float4 x4 = reinterpret_cast<const float4*>(xrow)[ii];
    const float* wr = w1q + (ii * 4) * 160;
#pragma unroll
    for (int u = 0; u < 4; ++u) {
      float xi = (u == 0) ? x4.x : (u == 1) ? x4.y : (u == 2) ? x4.z : x4.w;
      const float* w = wr + u * 160;
#pragma unroll
      for (int r = 0; r < 32; r += 4) {           // 8x ds_read_b128 broadcast
        float4 w4 = *reinterpret_cast<const float4*>(w + r);
        h[r + 0] = fmaf(xi, w4.x, h[r + 0]);
        h[r + 1] = fmaf(xi, w4.y, h[r + 1]);
        h[r + 2] = fmaf(xi, w4.z, h[r + 2]);
        h[r + 3] = fmaf(xi, w4.w, h[r + 3]);
      }
    }
  }
#pragma unroll
  for (int r = 0; r < 32; ++r) h[r] = fmaxf(h[r], 0.f);

  // ---- Phase 2: acc[64] partials over this lane's k-quarter ----------------
  float acc[64];
#pragma unroll
  for (int r = 0; r < 64; ++r) acc[r] = 0.f;

  const float* w2q = sW2 + q * 2056;
  int rot = (q & 1) << 4;        // j rotation within half
  int hi  = (q >> 1) << 5;       // j half base (0 or 32)

#pragma unroll
  for (int kl = 0; kl < 32; ++kl) {
    float hk = h[kl];
    const float* wr = w2q + kl * 64;
#pragma unroll
    for (int g = 0; g < 16; ++g) {
      int j = (hi ^ ((g >> 3) << 5)) | ((rot + ((g << 2) & 31)) & 31);
      float4 w4 = *reinterpret_cast<const float4*>(wr + j);
      acc[4 * g + 0] = fmaf(hk, w4.x, acc[4 * g + 0]);
      acc[4 * g + 1] = fmaf(hk, w4.y, acc[4 * g + 1]);
      acc[4 * g + 2] = fmaf(hk, w4.z, acc[4 * g + 2]);
      acc[4 * g + 3] = fmaf(hk, w4.w, acc[4 * g + 3]);
    }
  }

  // ---- In-register reduce-scatter across the 4 lanes of the node -----------
#pragma unroll
  for (int r = 0; r < 32; ++r) acc[r] += __shfl_xor(acc[32 + r], 2);
#pragma unroll
  for (int r = 0; r < 16; ++r) acc[r] += __shfl_xor(acc[16 + r], 1);

  // lane q now holds out[16q .. 16q+16): add b2, store coalesced.
  float* orow = out + (size_t)n * D_FEAT + (q << 4);
  const float4* b2q = reinterpret_cast<const float4*>(sB2 + (q << 4));
#pragma unroll
  for (int v = 0; v < 4; ++v) {
    float4 b = b2q[v];
    reinterpret_cast<float4*>(orow)[v] =
        make_float4(acc[4 * v + 0] + b.x, acc[4 * v + 1] + b.y,
                    acc[4 * v + 2] + b.z, acc[4 * v + 3] + b.w);
  }
}

// ---------------------------------------------------------------------------
// Launch
// ---------------------------------------------------------------------------
extern "C" void kernel_launch(void* const* d_in, const int* in_sizes, int n_in,
                              void* d_out, int out_size, void* d_ws, size_t ws_size,
                              hipStream_t stream) {
  const int*   edge_index = (const int*)d_in[0];    // [2, E]
  const float* edge_attr  = (const float*)d_in[1];  // [E, 64]
  const float* W1         = (const float*)d_in[3];  // [64, 128]
  const float* b1         = (const float*)d_in[4];  // [128]
  const float* W2         = (const float*)d_in[5];  // [128, 64]
  const float* b2         = (const float*)d_in[6];  // [64]
  float* out = (float*)d_out;

  const int E = in_sizes[1] / D_FEAT;   // 1,600,000
  const int N = out_size / D_FEAT;      // 100,000
  const int twoE = 2 * E;
  const int nb = (N + 1023) / 1024;     // 98 scan blocks

  int* deg   = (int*)d_ws;      // [N]
  int* off   = deg + N;         // [N]
  int* btot  = off + N;         // [1024]
  int* bbase = btot + 1024;     // [1024]
  int* elist = bbase + 1024;    // [2E]

  hipMemsetAsync(deg, 0, (size_t)N * sizeof(int), stream);
  count_deg_kernel<<<(twoE + 255) / 256, 256, 0, stream>>>(edge_index, deg, twoE);
  scanA_kernel<<<nb, 1024, 0, stream>>>(deg, off, btot, N);
  scanB_kernel<<<1, 1024, 0, stream>>>(btot, bbase, nb);
  scanC_kernel<<<(N + 255) / 256, 256, 0, stream>>>(off, bbase, N);
  fill_kernel<<<(twoE + 255) / 256, 256, 0, stream>>>(edge_index, off, elist, E);

  gather_kernel<<<(N + 3) / 4, 256, 0, stream>>>(deg, off, elist, edge_attr,
                                                 out, N);
  mlp4_kernel<<<(N + 63) / 64, 256, 0, stream>>>(W1, b1, W2, b2, out, N);
}

// Round 3
// 725.965 us; speedup vs baseline: 1.8459x; 1.5168x over previous
//
#include <hip/hip_runtime.h>
#include <cstdint>
#include <cstddef>

// Problem shape (fixed by the reference): E=1.6M, D=64, H=128, N=100k.
#define D_FEAT 64
#define H_HID 128

// Bucket sort parameters: 512 nodes per bucket -> 196 buckets; mean bucket
// size 2E/196 = 16,327 entries, sigma ~128 -> CAP = 18432 (mean + 16 sigma).
#define NBK_SHIFT 9
#define NBK_MASK 511
#define MAXBKT 256      // histogram width (>= nbkt = 196)
#define TILE 8192       // edges per workgroup tile in count/scatter passes
#define CAP 18432       // per-bucket LDS capacity in the sort pass

// ---------------------------------------------------------------------------
// Workspace (13.6 MB): bktCnt[256], bktOff[256], bktCur[256], deg[N],
// off_end[N], gbkt[2E] (packed (localnode<<21)|edge; becomes elist in-place).
// flow[N][64] lives in d_out (gather writes it, MLP reads row n before
// overwriting row n -- same thread-quad, program order).
// ---------------------------------------------------------------------------

// 1. Coarse histogram: LDS-privatized counts, ~196 global atomics per tile.
__global__ __launch_bounds__(1024) void bktcount_kernel(
    const int* __restrict__ idx, int* __restrict__ bktCnt, int twoE) {
  __shared__ int cnt[MAXBKT];
  if (threadIdx.x < MAXBKT) cnt[threadIdx.x] = 0;
  __syncthreads();
  int base = blockIdx.x * TILE;
#pragma unroll
  for (int k = 0; k < TILE / 1024; ++k) {
    int t = base + k * 1024 + threadIdx.x;
    if (t < twoE) atomicAdd(&cnt[idx[t] >> NBK_SHIFT], 1);
  }
  __syncthreads();
  if (threadIdx.x < MAXBKT) {
    int c = cnt[threadIdx.x];
    if (c) atomicAdd(&bktCnt[threadIdx.x], c);
  }
}

// 2. Exclusive scan of the 196 bucket counts; also seeds the atomic cursors.
__global__ __launch_bounds__(256) void bktscan_kernel(
    const int* __restrict__ bktCnt, int* __restrict__ bktOff,
    int* __restrict__ bktCur, int nbkt) {
  __shared__ int s[256];
  int v = (threadIdx.x < nbkt) ? bktCnt[threadIdx.x] : 0;
  s[threadIdx.x] = v;
  __syncthreads();
  for (int d = 1; d < 256; d <<= 1) {
    int t = (threadIdx.x >= d) ? s[threadIdx.x - d] : 0;
    __syncthreads();
    s[threadIdx.x] += t;
    __syncthreads();
  }
  if (threadIdx.x < nbkt) {
    int e = s[threadIdx.x] - v;
    bktOff[threadIdx.x] = e;
    bktCur[threadIdx.x] = e;
  }
}

// 3. Bucket scatter with LDS staging: each tile ranks its edges per bucket in
// LDS, reserves one contiguous run per (tile,bucket) with a single global
// atomic, reorders bucket-grouped in LDS, then streams out coalesced runs
// (avg 42 entries = 168B contiguous). Kills the 16x write amplification of
// the old random 4B scatter.
__global__ __launch_bounds__(1024) void bktscatter_kernel(
    const int* __restrict__ idx, int* __restrict__ bktCur,
    unsigned int* __restrict__ gbkt, int E, int twoE) {
  __shared__ int cnt[MAXBKT];
  __shared__ int lofs[MAXBKT];            // exclusive local offsets
  __shared__ int delta[MAXBKT];           // global runbase - lofs
  __shared__ unsigned int sval[TILE];     // packed (ln<<21)|e, bucket-grouped
  __shared__ unsigned short sbid[TILE];   // bucket id per staged slot

  if (threadIdx.x < MAXBKT) cnt[threadIdx.x] = 0;
  __syncthreads();

  int base = blockIdx.x * TILE;
  int myb[8], myr[8];
  unsigned int myv[8];
  int m = 0;
#pragma unroll
  for (int k = 0; k < 8; ++k) {
    int t = base + k * 1024 + threadIdx.x;
    if (t < twoE) {
      int node = idx[t];
      int b = node >> NBK_SHIFT;
      int e = (t < E) ? t : t - E;                      // edge id (< 2^21)
      myb[m] = b;
      myv[m] = ((unsigned int)(node & NBK_MASK) << 21) | (unsigned int)e;
      myr[m] = atomicAdd(&cnt[b], 1);                   // local rank
      ++m;
    }
  }
  __syncthreads();

  // Exclusive scan cnt -> lofs (256 lanes active; all 1024 hit barriers).
  {
    int v = (threadIdx.x < MAXBKT) ? cnt[threadIdx.x] : 0;
    if (threadIdx.x < MAXBKT) lofs[threadIdx.x] = v;
    __syncthreads();
    for (int d = 1; d < MAXBKT; d <<= 1) {
      int t = (threadIdx.x >= d && threadIdx.x < MAXBKT) ? lofs[threadIdx.x - d] : 0;
      __syncthreads();
      if (threadIdx.x < MAXBKT) lofs[threadIdx.x] += t;
      __syncthreads();
    }
    if (threadIdx.x < MAXBKT) lofs[threadIdx.x] -= v;   // exclusive
  }
  __syncthreads();

  // One global reservation per nonzero bucket.
  if (threadIdx.x < MAXBKT) {
    int c = cnt[threadIdx.x];
    int rb = c ? atomicAdd(&bktCur[threadIdx.x], c) : 0;
    delta[threadIdx.x] = rb - lofs[threadIdx.x];
  }
  __syncthreads();

  // Stage bucket-grouped.
  for (int k = 0; k < m; ++k) {
    int slot = lofs[myb[k]] + myr[k];
    sval[slot] = myv[k];
    sbid[slot] = (unsigned short)myb[k];
  }
  __syncthreads();

  // Stream out: consecutive slots -> consecutive global addrs within runs.
  int tot = min(TILE, twoE - base);
  for (int s = threadIdx.x; s < tot; s += 1024) {
    gbkt[delta[sbid[s]] + s] = sval[s];
  }
}

// 4. Per-bucket counting sort (one WG per bucket, in place): hist over the
// bucket's 512 nodes, LDS scan, reorder into LDS, stream back coalesced.
// Also emits deg[] and off_end[] (CSR) directly from the scan.
__global__ __launch_bounds__(1024) void bktsort_kernel(
    const int* __restrict__ bktCnt, const int* __restrict__ bktOff,
    unsigned int* __restrict__ gbkt,    // in: packed entries; out: elist
    int* __restrict__ deg, int* __restrict__ off_end, int N) {
  __shared__ int hist[512];
  __shared__ int cur[512];
  __shared__ unsigned int sorted[CAP];

  int b = blockIdx.x;
  int base = bktOff[b];
  int sz = bktCnt[b];
  if (sz > CAP) sz = CAP;   // defensive (CAP = mean + 16 sigma)

  if (threadIdx.x < 512) hist[threadIdx.x] = 0;
  __syncthreads();

  for (int s = threadIdx.x; s < sz; s += 1024)
    atomicAdd(&hist[gbkt[base + s] >> 21], 1);
  __syncthreads();

  // Exclusive scan hist -> cur (512 lanes active; all hit barriers).
  {
    int v = (threadIdx.x < 512) ? hist[threadIdx.x] : 0;
    if (threadIdx.x < 512) cur[threadIdx.x] = v;
    __syncthreads();
    for (int d = 1; d < 512; d <<= 1) {
      int t = (threadIdx.x >= d && threadIdx.x < 512) ? cur[threadIdx.x - d] : 0;
      __syncthreads();
      if (threadIdx.x < 512) cur[threadIdx.x] += t;
      __syncthreads();
    }
    if (threadIdx.x < 512) cur[threadIdx.x] -= v;       // exclusive start
  }
  __syncthreads();

  // Place entries by node (order within node arbitrary; sum is commutative).
  for (int s = threadIdx.x; s < sz; s += 1024) {
    unsigned int v = gbkt[base + s];
    int p = atomicAdd(&cur[v >> 21], 1);
    if (p < CAP) sorted[p] = v & 0x1FFFFFu;
  }
  __syncthreads();

  // Stream back in place: gbkt[base..base+sz) is now elist for this bucket.
  for (int s = threadIdx.x; s < sz; s += 1024)
    gbkt[base + s] = sorted[s];

  // CSR outputs: cur[ln] is now the segment END for local node ln.
  if (threadIdx.x < 512) {
    int n = (b << NBK_SHIFT) + threadIdx.x;
    if (n < N) {
      deg[n] = hist[threadIdx.x];
      off_end[n] = base + cur[threadIdx.x];
    }
  }
}

// 5. Gather-only: one wave per node, 4 waves/block. 16-lane groups pull whole
// 256B attr rows (float4/lane, coalesced); xor-shuffle reduce; lanes 0..15
// store the 256B flow row.
__global__ __launch_bounds__(256) void gather_kernel(
    const int* __restrict__ deg, const int* __restrict__ off_end,
    const int* __restrict__ elist, const float* __restrict__ attr,
    float* __restrict__ flow, int N) {
  int wave = threadIdx.x >> 6;
  int lane = threadIdx.x & 63;
  int n = blockIdx.x * 4 + wave;
  if (n >= N) return;

  int end = off_end[n];
  int start = end - deg[n];
  int g = lane >> 4;   // edge subgroup 0..3
  int l = lane & 15;   // float4 slot within the 256B row

  float a0 = 0.f, a1 = 0.f, a2 = 0.f, a3 = 0.f;
  int p = start + g;
  for (; p + 4 < end; p += 8) {
    int e0 = elist[p];
    int e1 = elist[p + 4];
    float4 v0 = reinterpret_cast<const float4*>(attr)[(size_t)e0 * 16 + l];
    float4 v1 = reinterpret_cast<const float4*>(attr)[(size_t)e1 * 16 + l];
    a0 += v0.x + v1.x; a1 += v0.y + v1.y;
    a2 += v0.z + v1.z; a3 += v0.w + v1.w;
  }
  if (p < end) {
    int e0 = elist[p];
    float4 v0 = reinterpret_cast<const float4*>(attr)[(size_t)e0 * 16 + l];
    a0 += v0.x; a1 += v0.y; a2 += v0.z; a3 += v0.w;
  }
  a0 += __shfl_xor(a0, 16); a0 += __shfl_xor(a0, 32);
  a1 += __shfl_xor(a1, 16); a1 += __shfl_xor(a1, 32);
  a2 += __shfl_xor(a2, 16); a2 += __shfl_xor(a2, 32);
  a3 += __shfl_xor(a3, 16); a3 += __shfl_xor(a3, 32);

  if (g == 0) {
    reinterpret_cast<float4*>(flow)[(size_t)n * 16 + l] =
        make_float4(a0, a1, a2, a3);
  }
}

// ---------------------------------------------------------------------------
// 6. MLP, spill-free: 4 lanes per node (q = lane&3). Lane q computes an
// h-quarter and partials of all 64 outputs in a lane-rotated register order;
// a static-index shfl_xor reduce-scatter leaves lane q with out[16q..16q+16).
// ---------------------------------------------------------------------------
__global__ __launch_bounds__(256, 2) void mlp4_kernel(
    const float* __restrict__ W1, const float* __restrict__ b1,
    const float* __restrict__ W2, const float* __restrict__ b2,
    float* __restrict__ out, int N) {
  __shared__ __align__(16) float sW1[64 * 160];   // [i][quarter(40f)]
  __shared__ __align__(16) float sW2[4 * 2056];   // [quarter][k&31][64]
  __shared__ __align__(16) float sB1[H_HID];
  __shared__ __align__(16) float sB2[D_FEAT];

  for (int t = threadIdx.x; t < 64 * 128; t += 256) {
    int i = t >> 7, k = t & 127;
    sW1[i * 160 + (k >> 5) * 40 + (k & 31)] = W1[t];
  }
  for (int t = threadIdx.x; t < 128 * 64; t += 256) {
    int k = t >> 6, j = t & 63;
    sW2[(k >> 5) * 2056 + (k & 31) * 64 + j] = W2[t];
  }
  if (threadIdx.x < H_HID) sB1[threadIdx.x] = b1[threadIdx.x];
  if (threadIdx.x < D_FEAT) sB2[threadIdx.x] = b2[threadIdx.x];
  __syncthreads();

  int n = blockIdx.x * 64 + (threadIdx.x >> 2);   // node
  int q = threadIdx.x & 3;                        // k-quarter / j-slice
  if (n >= N) return;

  const float* xrow = out + (size_t)n * D_FEAT;   // flow row (read-before-write)

  float h[32];
  {
    const float4* b1q = reinterpret_cast<const float4*>(sB1 + (q << 5));
#pragma unroll
    for (int v = 0; v < 8; ++v) {
      float4 b = b1q[v];
      h[4 * v + 0] = b.x; h[4 * v + 1] = b.y;
      h[4 * v + 2] = b.z; h[4 * v + 3] = b.w;
    }
  }
  const float* w1q = sW1 + q * 40;
  for (int ii = 0; ii < 16; ++ii) {
    float4 x4 = reinterpret_cast<const float4*>(xrow)[ii];
    const float* wr = w1q + (ii * 4) * 160;
#pragma unroll
    for (int u = 0; u < 4; ++u) {
      float xi = (u == 0) ? x4.x : (u == 1) ? x4.y : (u == 2) ? x4.z : x4.w;
      const float* w = wr + u * 160;
#pragma unroll
      for (int r = 0; r < 32; r += 4) {
        float4 w4 = *reinterpret_cast<const float4*>(w + r);
        h[r + 0] = fmaf(xi, w4.x, h[r + 0]);
        h[r + 1] = fmaf(xi, w4.y, h[r + 1]);
        h[r + 2] = fmaf(xi, w4.z, h[r + 2]);
        h[r + 3] = fmaf(xi, w4.w, h[r + 3]);
      }
    }
  }
#pragma unroll
  for (int r = 0; r < 32; ++r) h[r] = fmaxf(h[r], 0.f);

  float acc[64];
#pragma unroll
  for (int r = 0; r < 64; ++r) acc[r] = 0.f;

  const float* w2q = sW2 + q * 2056;
  int rot = (q & 1) << 4;
  int hi  = (q >> 1) << 5;

#pragma unroll
  for (int kl = 0; kl < 32; ++kl) {
    float hk = h[kl];
    const float* wr = w2q + kl * 64;
#pragma unroll
    for (int g = 0; g < 16; ++g) {
      int j = (hi ^ ((g >> 3) << 5)) | ((rot + ((g << 2) & 31)) & 31);
      float4 w4 = *reinterpret_cast<const float4*>(wr + j);
      acc[4 * g + 0] = fmaf(hk, w4.x, acc[4 * g + 0]);
      acc[4 * g + 1] = fmaf(hk, w4.y, acc[4 * g + 1]);
      acc[4 * g + 2] = fmaf(hk, w4.z, acc[4 * g + 2]);
      acc[4 * g + 3] = fmaf(hk, w4.w, acc[4 * g + 3]);
    }
  }

#pragma unroll
  for (int r = 0; r < 32; ++r) acc[r] += __shfl_xor(acc[32 + r], 2);
#pragma unroll
  for (int r = 0; r < 16; ++r) acc[r] += __shfl_xor(acc[16 + r], 1);

  float* orow = out + (size_t)n * D_FEAT + (q << 4);
  const float4* b2q = reinterpret_cast<const float4*>(sB2 + (q << 4));
#pragma unroll
  for (int v = 0; v < 4; ++v) {
    float4 b = b2q[v];
    reinterpret_cast<float4*>(orow)[v] =
        make_float4(acc[4 * v + 0] + b.x, acc[4 * v + 1] + b.y,
                    acc[4 * v + 2] + b.z, acc[4 * v + 3] + b.w);
  }
}

// ---------------------------------------------------------------------------
// Launch
// ---------------------------------------------------------------------------
extern "C" void kernel_launch(void* const* d_in, const int* in_sizes, int n_in,
                              void* d_out, int out_size, void* d_ws, size_t ws_size,
                              hipStream_t stream) {
  const int*   edge_index = (const int*)d_in[0];    // [2, E]
  const float* edge_attr  = (const float*)d_in[1];  // [E, 64]
  const float* W1         = (const float*)d_in[3];  // [64, 128]
  const float* b1         = (const float*)d_in[4];  // [128]
  const float* W2         = (const float*)d_in[5];  // [128, 64]
  const float* b2         = (const float*)d_in[6];  // [64]
  float* out = (float*)d_out;

  const int E = in_sizes[1] / D_FEAT;   // 1,600,000
  const int N = out_size / D_FEAT;      // 100,000
  const int twoE = 2 * E;
  const int nbkt = (N + NBK_MASK) >> NBK_SHIFT;       // 196
  const int ntile = (twoE + TILE - 1) / TILE;         // 391

  int* bktCnt = (int*)d_ws;             // [256]
  int* bktOff = bktCnt + 256;           // [256]
  int* bktCur = bktOff + 256;           // [256]
  int* deg    = bktCur + 256;           // [N]
  int* off_end = deg + N;               // [N]
  unsigned int* gbkt = (unsigned int*)(off_end + N);  // [2E], becomes elist

  hipMemsetAsync(bktCnt, 0, 256 * sizeof(int), stream);
  bktcount_kernel<<<ntile, 1024, 0, stream>>>(edge_index, bktCnt, twoE);
  bktscan_kernel<<<1, 256, 0, stream>>>(bktCnt, bktOff, bktCur, nbkt);
  bktscatter_kernel<<<ntile, 1024, 0, stream>>>(edge_index, bktCur, gbkt, E, twoE);
  bktsort_kernel<<<nbkt, 1024, 0, stream>>>(bktCnt, bktOff, gbkt, deg, off_end, N);

  gather_kernel<<<(N + 3) / 4, 256, 0, stream>>>(deg, off_end,
                                                 (const int*)gbkt, edge_attr,
                                                 out, N);
  mlp4_kernel<<<(N + 63) / 64, 256, 0, stream>>>(W1, b1, W2, b2, out, N);
}